// Round 6
// baseline (366.364 us; speedup 1.0000x reference)
//
#include <hip/hip_runtime.h>
#include <hip/hip_bf16.h>
#include <stdint.h>

typedef __attribute__((ext_vector_type(8))) short short8;
typedef __attribute__((ext_vector_type(4))) float f32x4;
typedef unsigned short ushort_t;

#define MFMA16(a, b, c) __builtin_amdgcn_mfma_f32_16x16x32_bf16((a), (b), (c), 0, 0, 0)
#define EXP2F(x) __builtin_amdgcn_exp2f(x)

// B=8 S=1024 D=1024 H=16 hd=64; M = B*S = 8192; N = 3*D = 3072; K = 1024

__device__ __forceinline__ float bf2f(unsigned short u) {
    union { unsigned int i; float f; } x; x.i = ((unsigned int)u) << 16; return x.f;
}
__device__ __forceinline__ unsigned short f2bf(float f) {
    union { float f; unsigned int i; } x; x.f = f;
    unsigned int i = x.i;
    i = i + 0x7FFFu + ((i >> 16) & 1u);   // RNE
    return (unsigned short)(i >> 16);
}
__device__ __forceinline__ unsigned int pack2(float a, float b) {
    return (unsigned int)f2bf(a) | ((unsigned int)f2bf(b) << 16);
}
__device__ __forceinline__ void glds16(const void* gsrc, void* ldst) {
    __builtin_amdgcn_global_load_lds(
        (const __attribute__((address_space(1))) unsigned int*)gsrc,
        (__attribute__((address_space(3))) unsigned int*)ldst, 16, 0, 0);
}

// ---------------- kernel 0: fp32 -> bf16 pre-pass for H and W ----------------
__global__ __launch_bounds__(256) void conv_bf16_kernel(
    const float4* __restrict__ H,   // 8192*1024 floats = 2097152 float4
    const float4* __restrict__ W,   // 3072*1024 floats =  786432 float4
    uint2* __restrict__ Hb,
    uint2* __restrict__ Wb)
{
    const size_t HN4 = 2097152;
    size_t i = (size_t)blockIdx.x * 256 + threadIdx.x;   // 0 .. 2883583
    const float4* src; uint2* dst; size_t j;
    if (i < HN4) { src = H; dst = Hb; j = i; }
    else         { src = W; dst = Wb; j = i - HN4; }
    float4 v = src[j];
    uint2 o; o.x = pack2(v.x, v.y); o.y = pack2(v.z, v.w);
    dst[j] = o;
}

// ---------------- kernel 1: lo(b,s,r) = sum_d hidden[b,s,d] * loraA[a_b][r][d] ----------------
__global__ __launch_bounds__(64) void lora_lo_kernel(
    const float* __restrict__ hidden,
    const float* __restrict__ loraA,
    const int* __restrict__ adapter_mask,
    float4* __restrict__ lo)
{
    int bs = blockIdx.x;          // 0..8191
    int lane = threadIdx.x;       // 0..63
    int b = bs >> 10;
    int a = adapter_mask[b];
    const float* hp = hidden + (size_t)bs * 1024 + lane * 16;
    const float* Ap = loraA + (size_t)a * 4096 + lane * 16;
    float hv[16];
    for (int j = 0; j < 16; ++j) hv[j] = hp[j];
    float acc[4];
    for (int r = 0; r < 4; ++r) {
        const float* ap = Ap + r * 1024;
        float s = 0.f;
        for (int j = 0; j < 16; ++j) s += hv[j] * ap[j];
        acc[r] = s;
    }
    for (int off = 32; off > 0; off >>= 1)
        for (int r = 0; r < 4; ++r) acc[r] += __shfl_xor(acc[r], off);
    if (lane == 0) lo[bs] = make_float4(acc[0], acc[1], acc[2], acc[3]);
}

// ---------------- kernel 2: qkv = Hb @ Wb^T + bias + 0.25 * lo @ B_t^T, fused RoPE ----------------
// q,k -> (B,H,S,hd) bf16 with RoPE applied; v -> transposed (B,H,hd,S) bf16
__global__ __launch_bounds__(256) void qkv_gemm_kernel(
    const ushort_t* __restrict__ Hb,   // (8192,1024) bf16
    const ushort_t* __restrict__ Wb,   // (3072,1024) bf16
    const float* __restrict__ bias,    // (3072)
    const float4* __restrict__ lo,     // (8192)
    const float* __restrict__ loraB,   // (5,3072,4)
    const int* __restrict__ adapter_mask, // (8)
    const float* __restrict__ cosp,    // (8,1024,64)
    const float* __restrict__ sinp,
    ushort_t* __restrict__ qw,
    ushort_t* __restrict__ kw,
    ushort_t* __restrict__ vt)
{
    __shared__ __align__(16) ushort_t As[128 * 32];   // no pad: global_load_lds layout
    __shared__ __align__(16) ushort_t Bs[128 * 32];
    int tid = threadIdx.x;
    int wave = tid >> 6, lane = tid & 63, quad = lane >> 4, l16 = lane & 15;
    int n0 = blockIdx.x * 128;
    int m0 = blockIdx.y * 128;
    int mq = (wave >> 1) * 64, nq = (wave & 1) * 64;

    f32x4 acc[4][4];
    for (int i = 0; i < 4; ++i) for (int j = 0; j < 4; ++j) acc[i][j] = (f32x4)0.f;

    const ushort_t* gA0 = Hb + (size_t)(m0 + (tid >> 2)) * 1024 + (tid & 3) * 8;
    const ushort_t* gA1 = gA0 + (size_t)64 * 1024;
    const ushort_t* gB0 = Wb + (size_t)(n0 + (tid >> 2)) * 1024 + (tid & 3) * 8;
    const ushort_t* gB1 = gB0 + (size_t)64 * 1024;
    char* ldsA0 = (char*)As + wave * 1024;            // + lane*16 implicit
    char* ldsA1 = ldsA0 + 4096;
    char* ldsB0 = (char*)Bs + wave * 1024;
    char* ldsB1 = ldsB0 + 4096;

    for (int kk = 0; kk < 1024; kk += 32) {
        glds16(gA0 + kk, ldsA0);
        glds16(gA1 + kk, ldsA1);
        glds16(gB0 + kk, ldsB0);
        glds16(gB1 + kk, ldsB1);
        __syncthreads();
        short8 af[4], bf[4];
        for (int mi = 0; mi < 4; ++mi)
            af[mi] = *(const short8*)&As[(mq + mi * 16 + l16) * 32 + quad * 8];
        for (int ni = 0; ni < 4; ++ni)
            bf[ni] = *(const short8*)&Bs[(nq + ni * 16 + l16) * 32 + quad * 8];
        for (int mi = 0; mi < 4; ++mi)
            for (int ni = 0; ni < 4; ++ni)
                acc[mi][ni] = MFMA16(af[mi], bf[ni], acc[mi][ni]);
        __syncthreads();
    }

    // epilogue: bias + lora + rope + scatter
    int t = n0 >> 10;            // 0=q 1=k 2=v, block-uniform (128 | 1024)
    int b = m0 >> 10;            // block-uniform
    int a = adapter_mask[b];
    float bi[4], bb[4][4];
    int cpos[4], chh[4];
    for (int ni = 0; ni < 4; ++ni) {
        int c = n0 + nq + ni * 16 + l16;
        bi[ni] = bias[c];
        const float* Bp = loraB + ((size_t)a * 3072 + c) * 4;
        bb[ni][0] = Bp[0]; bb[ni][1] = Bp[1]; bb[ni][2] = Bp[2]; bb[ni][3] = Bp[3];
        cpos[ni] = c & 63; chh[ni] = (c >> 6) & 15;
    }
    for (int mi = 0; mi < 4; ++mi) {
        for (int r = 0; r < 4; ++r) {
            int m = m0 + mq + mi * 16 + quad * 4 + r;
            int s = m & 1023;
            float4 lov = lo[m];
            float v[4];
            for (int ni = 0; ni < 4; ++ni)
                v[ni] = acc[mi][ni][r] + bi[ni]
                      + 0.25f * (lov.x * bb[ni][0] + lov.y * bb[ni][1]
                               + lov.z * bb[ni][2] + lov.w * bb[ni][3]);
            if (t < 2) {
                // rope: pos = ni*16+l16 for ni<2, partner at ni+2 (pos+32); cos[pos+32]==cos[pos]
                size_t cb = ((size_t)b * 1024 + s) * 64;
                float cA = cosp[cb + l16],      sA = sinp[cb + l16];
                float cB = cosp[cb + 16 + l16], sB = sinp[cb + 16 + l16];
                float w0 = v[0] * cA - v[2] * sA;
                float w2 = v[2] * cA + v[0] * sA;
                float w1 = v[1] * cB - v[3] * sB;
                float w3 = v[3] * cB + v[1] * sB;
                v[0] = w0; v[1] = w1; v[2] = w2; v[3] = w3;
            }
            for (int ni = 0; ni < 4; ++ni) {
                unsigned short ob = f2bf(v[ni]);
                size_t bh = (size_t)b * 16 + chh[ni];
                if (t == 0)      qw[(bh * 1024 + s) * 64 + cpos[ni]] = ob;
                else if (t == 1) kw[(bh * 1024 + s) * 64 + cpos[ni]] = ob;
                else             vt[(bh * 64 + cpos[ni]) * 1024 + s] = ob;
            }
        }
    }
}

// ---------------- kernel 3: attention ----------------
// grid 2048 = 16 q-tiles(64 rows) x 128 bh; id%8 == bh%8 (XCD-local K/V).
// K tiles double-buffered in LDS via glds16; each wave owns 16 q-rows.
__global__ __launch_bounds__(256) void attn_kernel(
    const ushort_t* __restrict__ qw,   // (B,H,S,hd) bf16 (rope applied)
    const ushort_t* __restrict__ kw,   // (B,H,S,hd) bf16 (rope applied)
    const ushort_t* __restrict__ vt,   // (B,H,hd,S) bf16
    const float* __restrict__ mask,    // (B,1,1,S) f32
    float* __restrict__ out)           // (B,S,H*hd) f32
{
    __shared__ __align__(16) ushort_t Ks[2][2][64 * 32]; // [buf][d-half][row*32+col], 16KB
    __shared__ __align__(16) ushort_t Ps[4][16][72];     // per-wave, 9.2KB
    const float KSCALE = 0.125f * 1.44269504f;
    const float MSCALE = 1.44269504f;
    int tid = threadIdx.x;
    int wave = tid >> 6, lane = tid & 63, quad = lane >> 4, l16 = lane & 15;
    int id = blockIdx.x;
    int qt = id >> 7;             // 0..15
    int bh = id & 127;            // 0..127
    int b = bh >> 4, h = bh & 15;
    size_t base = (size_t)bh * 1024 * 64;
    int q0 = qt * 64 + wave * 16;

    short8 ones;
    for (int j = 0; j < 8; ++j) ones[j] = (short)0x3F80;   // bf16 1.0

    short8 qf[2];
    for (int kt = 0; kt < 2; ++kt)
        qf[kt] = *(const short8*)(qw + base + (size_t)(q0 + l16) * 64 + kt * 32 + quad * 8);

    f32x4 oacc[4], sum_acc;
    sum_acc = (f32x4)0.f;
    for (int nt = 0; nt < 4; ++nt) oacc[nt] = (f32x4)0.f;

    // prefetch K tile 0 (wave w stages rows w*16..w*16+15 of each d-half)
    for (int hh = 0; hh < 2; ++hh)
        glds16(kw + base + (size_t)(wave * 16 + (lane >> 2)) * 64 + hh * 32 + (lane & 3) * 8,
               &Ks[0][hh][wave * 512]);

    for (int it = 0; it < 16; ++it) {
        int cur = it & 1;
        int kt0 = it * 64;
        __syncthreads();          // drains vmcnt(0): prefetch into Ks[cur] complete
        if (it < 15) {
            int kn = kt0 + 64;
            for (int hh = 0; hh < 2; ++hh)
                glds16(kw + base + (size_t)(kn + wave * 16 + (lane >> 2)) * 64 + hh * 32 + (lane & 3) * 8,
                       &Ks[cur ^ 1][hh][wave * 512]);
        }
        // V loads early (global, consumed last)
        short8 vf[4][2];
        for (int nt = 0; nt < 4; ++nt)
            for (int kt = 0; kt < 2; ++kt)
                vf[nt][kt] = *(const short8*)(vt + base + (size_t)(nt * 16 + l16) * 1024 + kt0 + kt * 32 + quad * 8);
        float mv[4];
        for (int nt = 0; nt < 4; ++nt) mv[nt] = mask[b * 1024 + kt0 + nt * 16 + l16] * MSCALE;
        // K frags from LDS (conflict-free 1KB/16-row pattern)
        short8 kf[4][2];
        for (int nt = 0; nt < 4; ++nt)
            for (int kt = 0; kt < 2; ++kt)
                kf[nt][kt] = *(const short8*)&Ks[cur][kt][(nt * 16 + l16) * 32 + quad * 8];
        // S = Q K^T (16 q x 64 k per wave)
        f32x4 sacc[4];
        for (int nt = 0; nt < 4; ++nt) {
            f32x4 z = (f32x4)0.f;
            z = MFMA16(qf[0], kf[nt][0], z);
            z = MFMA16(qf[1], kf[nt][1], z);
            sacc[nt] = z;
        }
        // P = exp2(scale*S + mask'); exact (scores bounded, fp32-safe)
        for (int nt = 0; nt < 4; ++nt)
            for (int r = 0; r < 4; ++r) {
                float p = EXP2F(sacc[nt][r] * KSCALE + mv[nt]);
                Ps[wave][quad * 4 + r][nt * 16 + l16] = f2bf(p);
            }
        // per-wave LDS: in-wave ordering + lgkmcnt suffice (no barrier)
        short8 pf[2];
        for (int kt = 0; kt < 2; ++kt)
            pf[kt] = *(const short8*)&Ps[wave][l16][kt * 32 + quad * 8];
        for (int nt = 0; nt < 4; ++nt) {
            oacc[nt] = MFMA16(pf[0], vf[nt][0], oacc[nt]);
            oacc[nt] = MFMA16(pf[1], vf[nt][1], oacc[nt]);
        }
        sum_acc = MFMA16(pf[0], ones, sum_acc);   // row sums of P
        sum_acc = MFMA16(pf[1], ones, sum_acc);
    }
    for (int r = 0; r < 4; ++r) {
        float inv = 1.f / sum_acc[r];
        int s = q0 + quad * 4 + r;
        size_t ob = ((size_t)b * 1024 + s) * 1024 + h * 64;
        for (int nt = 0; nt < 4; ++nt)
            out[ob + nt * 16 + l16] = oacc[nt][r] * inv;
    }
}

extern "C" void kernel_launch(void* const* d_in, const int* in_sizes, int n_in,
                              void* d_out, int out_size, void* d_ws, size_t ws_size,
                              hipStream_t stream)
{
    const float* hidden = (const float*)d_in[0];
    const float* mask   = (const float*)d_in[1];
    const float* cosp   = (const float*)d_in[2];
    const float* sinp   = (const float*)d_in[3];
    const int* adapter_mask = (const int*)d_in[4];
    const float* W      = (const float*)d_in[5];
    const float* bias   = (const float*)d_in[6];
    const float* loraA  = (const float*)d_in[7];
    const float* loraB  = (const float*)d_in[8];
    float* out = (float*)d_out;

    char* ws = (char*)d_ws;
    float4* lo = (float4*)ws;                                  // 128 KB
    ushort_t* qw = (ushort_t*)(ws + (1 << 20));                // 16 MB each
    ushort_t* kw = qw + (size_t)8 * 16 * 1024 * 64;
    ushort_t* vt = kw + (size_t)8 * 16 * 1024 * 64;            // total 49 MB (proven fits)

    // bf16 copies of H and W live in d_out (32 MB); attn fully overwrites d_out afterwards
    ushort_t* Hb = (ushort_t*)d_out;                           // 16 MB
    ushort_t* Wb = Hb + (size_t)8192 * 1024;                   // 6 MB

    conv_bf16_kernel<<<11264, 256, 0, stream>>>((const float4*)hidden, (const float4*)W,
                                                (uint2*)Hb, (uint2*)Wb);
    lora_lo_kernel<<<8192, 64, 0, stream>>>(hidden, loraA, adapter_mask, lo);
    qkv_gemm_kernel<<<dim3(24, 64), 256, 0, stream>>>(Hb, Wb, bias, lo, loraB, adapter_mask,
                                                      cosp, sinp, qw, kw, vt);
    attn_kernel<<<2048, 256, 0, stream>>>(qw, kw, vt, mask, out);
}

// Round 7
// 349.804 us; speedup vs baseline: 1.0473x; 1.0473x over previous
//
#include <hip/hip_runtime.h>
#include <hip/hip_bf16.h>
#include <stdint.h>

typedef __attribute__((ext_vector_type(8))) short short8;
typedef __attribute__((ext_vector_type(4))) float f32x4;
typedef unsigned short ushort_t;

#define MFMA16(a, b, c) __builtin_amdgcn_mfma_f32_16x16x32_bf16((a), (b), (c), 0, 0, 0)
#define EXP2F(x) __builtin_amdgcn_exp2f(x)

// B=8 S=1024 D=1024 H=16 hd=64; M = B*S = 8192; N = 3*D = 3072; K = 1024

__device__ __forceinline__ float bf2f(unsigned short u) {
    union { unsigned int i; float f; } x; x.i = ((unsigned int)u) << 16; return x.f;
}
__device__ __forceinline__ unsigned short f2bf(float f) {
    union { float f; unsigned int i; } x; x.f = f;
    unsigned int i = x.i;
    i = i + 0x7FFFu + ((i >> 16) & 1u);   // RNE
    return (unsigned short)(i >> 16);
}
__device__ __forceinline__ unsigned int pack2(float a, float b) {
    return (unsigned int)f2bf(a) | ((unsigned int)f2bf(b) << 16);
}
__device__ __forceinline__ void glds16(const void* gsrc, void* ldst) {
    __builtin_amdgcn_global_load_lds(
        (const __attribute__((address_space(1))) unsigned int*)gsrc,
        (__attribute__((address_space(3))) unsigned int*)ldst, 16, 0, 0);
}

// ---------------- kernel 0: fp32 -> bf16 pre-pass for H and W ----------------
__global__ __launch_bounds__(256) void conv_bf16_kernel(
    const float4* __restrict__ H,   // 8192*1024 floats = 2097152 float4
    const float4* __restrict__ W,   // 3072*1024 floats =  786432 float4
    uint2* __restrict__ Hb,
    uint2* __restrict__ Wb)
{
    const size_t HN4 = 2097152;
    size_t i = (size_t)blockIdx.x * 256 + threadIdx.x;   // 0 .. 2883583
    const float4* src; uint2* dst; size_t j;
    if (i < HN4) { src = H; dst = Hb; j = i; }
    else         { src = W; dst = Wb; j = i - HN4; }
    float4 v = src[j];
    uint2 o; o.x = pack2(v.x, v.y); o.y = pack2(v.z, v.w);
    dst[j] = o;
}

// ---------------- kernel 1: lo(b,s,r) = sum_d hidden[b,s,d] * loraA[a_b][r][d] ----------------
__global__ __launch_bounds__(64) void lora_lo_kernel(
    const float* __restrict__ hidden,
    const float* __restrict__ loraA,
    const int* __restrict__ adapter_mask,
    float4* __restrict__ lo)
{
    int bs = blockIdx.x;          // 0..8191
    int lane = threadIdx.x;       // 0..63
    int b = bs >> 10;
    int a = adapter_mask[b];
    const float* hp = hidden + (size_t)bs * 1024 + lane * 16;
    const float* Ap = loraA + (size_t)a * 4096 + lane * 16;
    float hv[16];
    for (int j = 0; j < 16; ++j) hv[j] = hp[j];
    float acc[4];
    for (int r = 0; r < 4; ++r) {
        const float* ap = Ap + r * 1024;
        float s = 0.f;
        for (int j = 0; j < 16; ++j) s += hv[j] * ap[j];
        acc[r] = s;
    }
    for (int off = 32; off > 0; off >>= 1)
        for (int r = 0; r < 4; ++r) acc[r] += __shfl_xor(acc[r], off);
    if (lane == 0) lo[bs] = make_float4(acc[0], acc[1], acc[2], acc[3]);
}

// ---------------- kernel 2: qkv = Hb @ Wb^T + bias + 0.25 * lo @ B_t^T, fused RoPE ----------------
// q,k -> (B,H,S,hd) bf16 with RoPE applied; v -> transposed (B,H,hd,S) bf16
__global__ __launch_bounds__(256) void qkv_gemm_kernel(
    const ushort_t* __restrict__ Hb,   // (8192,1024) bf16
    const ushort_t* __restrict__ Wb,   // (3072,1024) bf16
    const float* __restrict__ bias,    // (3072)
    const float4* __restrict__ lo,     // (8192)
    const float* __restrict__ loraB,   // (5,3072,4)
    const int* __restrict__ adapter_mask, // (8)
    const float* __restrict__ cosp,    // (8,1024,64)
    const float* __restrict__ sinp,
    ushort_t* __restrict__ qw,
    ushort_t* __restrict__ kw,
    ushort_t* __restrict__ vt)
{
    __shared__ __align__(16) ushort_t As[128 * 32];   // no pad: global_load_lds layout
    __shared__ __align__(16) ushort_t Bs[128 * 32];
    int tid = threadIdx.x;
    int wave = tid >> 6, lane = tid & 63, quad = lane >> 4, l16 = lane & 15;
    int n0 = blockIdx.x * 128;
    int m0 = blockIdx.y * 128;
    int mq = (wave >> 1) * 64, nq = (wave & 1) * 64;

    f32x4 acc[4][4];
    for (int i = 0; i < 4; ++i) for (int j = 0; j < 4; ++j) acc[i][j] = (f32x4)0.f;

    const ushort_t* gA0 = Hb + (size_t)(m0 + (tid >> 2)) * 1024 + (tid & 3) * 8;
    const ushort_t* gA1 = gA0 + (size_t)64 * 1024;
    const ushort_t* gB0 = Wb + (size_t)(n0 + (tid >> 2)) * 1024 + (tid & 3) * 8;
    const ushort_t* gB1 = gB0 + (size_t)64 * 1024;
    char* ldsA0 = (char*)As + wave * 1024;            // + lane*16 implicit
    char* ldsA1 = ldsA0 + 4096;
    char* ldsB0 = (char*)Bs + wave * 1024;
    char* ldsB1 = ldsB0 + 4096;

    for (int kk = 0; kk < 1024; kk += 32) {
        glds16(gA0 + kk, ldsA0);
        glds16(gA1 + kk, ldsA1);
        glds16(gB0 + kk, ldsB0);
        glds16(gB1 + kk, ldsB1);
        __syncthreads();
        short8 af[4], bf[4];
        for (int mi = 0; mi < 4; ++mi)
            af[mi] = *(const short8*)&As[(mq + mi * 16 + l16) * 32 + quad * 8];
        for (int ni = 0; ni < 4; ++ni)
            bf[ni] = *(const short8*)&Bs[(nq + ni * 16 + l16) * 32 + quad * 8];
        for (int mi = 0; mi < 4; ++mi)
            for (int ni = 0; ni < 4; ++ni)
                acc[mi][ni] = MFMA16(af[mi], bf[ni], acc[mi][ni]);
        __syncthreads();
    }

    // epilogue: bias + lora + rope + scatter
    int t = n0 >> 10;            // 0=q 1=k 2=v, block-uniform (128 | 1024)
    int b = m0 >> 10;            // block-uniform
    int a = adapter_mask[b];
    float bi[4], bb[4][4];
    int cpos[4], chh[4];
    for (int ni = 0; ni < 4; ++ni) {
        int c = n0 + nq + ni * 16 + l16;
        bi[ni] = bias[c];
        const float* Bp = loraB + ((size_t)a * 3072 + c) * 4;
        bb[ni][0] = Bp[0]; bb[ni][1] = Bp[1]; bb[ni][2] = Bp[2]; bb[ni][3] = Bp[3];
        cpos[ni] = c & 63; chh[ni] = (c >> 6) & 15;
    }
    for (int mi = 0; mi < 4; ++mi) {
        for (int r = 0; r < 4; ++r) {
            int m = m0 + mq + mi * 16 + quad * 4 + r;
            int s = m & 1023;
            float4 lov = lo[m];
            float v[4];
            for (int ni = 0; ni < 4; ++ni)
                v[ni] = acc[mi][ni][r] + bi[ni]
                      + 0.25f * (lov.x * bb[ni][0] + lov.y * bb[ni][1]
                               + lov.z * bb[ni][2] + lov.w * bb[ni][3]);
            if (t < 2) {
                // rope: pos = ni*16+l16 for ni<2, partner at ni+2 (pos+32); cos[pos+32]==cos[pos]
                size_t cb = ((size_t)b * 1024 + s) * 64;
                float cA = cosp[cb + l16],      sA = sinp[cb + l16];
                float cB = cosp[cb + 16 + l16], sB = sinp[cb + 16 + l16];
                float w0 = v[0] * cA - v[2] * sA;
                float w2 = v[2] * cA + v[0] * sA;
                float w1 = v[1] * cB - v[3] * sB;
                float w3 = v[3] * cB + v[1] * sB;
                v[0] = w0; v[1] = w1; v[2] = w2; v[3] = w3;
            }
            for (int ni = 0; ni < 4; ++ni) {
                unsigned short ob = f2bf(v[ni]);
                size_t bh = (size_t)b * 16 + chh[ni];
                if (t == 0)      qw[(bh * 1024 + s) * 64 + cpos[ni]] = ob;
                else if (t == 1) kw[(bh * 1024 + s) * 64 + cpos[ni]] = ob;
                else             vt[(bh * 64 + cpos[ni]) * 1024 + s] = ob;
            }
        }
    }
}

// ---------------- kernel 3: attention (R5 structure + K register prefetch pipeline) ----------------
// grid 1024 = 8 q-tiles(128 rows) x 128 bh; id%8 == bh%8 -> XCD-local K/V (L2-resident 4MB/XCD).
// Per iteration issue order [mask, V(it), K(it+1)] so vmcnt drains never touch the K prefetch.
__global__ __launch_bounds__(256) void attn_kernel(
    const ushort_t* __restrict__ qw,   // (B,H,S,hd) bf16 (rope applied)
    const ushort_t* __restrict__ kw,   // (B,H,S,hd) bf16 (rope applied)
    const ushort_t* __restrict__ vt,   // (B,H,hd,S) bf16
    const float* __restrict__ mask,    // (B,1,1,S) f32
    float* __restrict__ out)           // (B,S,H*hd) f32
{
    __shared__ __align__(16) ushort_t Ps[4][32][72];   // per-wave
    const float KSCALE = 0.125f * 1.44269504f;
    const float MSCALE = 1.44269504f;
    int tid = threadIdx.x;
    int wave = tid >> 6, lane = tid & 63, quad = lane >> 4, l16 = lane & 15;
    int id = blockIdx.x;
    int qt = id >> 7;             // 0..7
    int bh = id & 127;            // 0..127
    int b = bh >> 4, h = bh & 15;
    size_t base = (size_t)bh * 1024 * 64;
    int q0 = qt * 128 + wave * 32;

    short8 ones;
    for (int j = 0; j < 8; ++j) ones[j] = (short)0x3F80;   // bf16 1.0

    const ushort_t* kbase = kw + base;
    const ushort_t* vbase = vt + base;

    short8 qf[2][2];
    for (int mt = 0; mt < 2; ++mt)
        for (int kt = 0; kt < 2; ++kt)
            qf[mt][kt] = *(const short8*)(qw + base + (size_t)(q0 + mt * 16 + l16) * 64 + kt * 32 + quad * 8);

    f32x4 oacc[2][4], sum_acc[2];
    for (int mt = 0; mt < 2; ++mt) {
        sum_acc[mt] = (f32x4)0.f;
        for (int nt = 0; nt < 4; ++nt) oacc[mt][nt] = (f32x4)0.f;
    }

    short8 kfA[4][2], kfB[4][2];
    // preload K tile 0 into kfA
    for (int nt = 0; nt < 4; ++nt)
        for (int kt = 0; kt < 2; ++kt)
            kfA[nt][kt] = *(const short8*)(kbase + (size_t)(nt * 16 + l16) * 64 + kt * 32 + quad * 8);

    auto body = [&](int it, short8 (&cur)[4][2], short8 (&nxt)[4][2]) {
        int kt0 = it * 64;
        // mask first (drained before exp), then V (drained before PV), then K prefetch (stays in flight)
        float mv[4];
        for (int nt = 0; nt < 4; ++nt) mv[nt] = mask[b * 1024 + kt0 + nt * 16 + l16] * MSCALE;
        short8 vf[4][2];
        for (int nt = 0; nt < 4; ++nt)
            for (int kt = 0; kt < 2; ++kt)
                vf[nt][kt] = *(const short8*)(vbase + (size_t)(nt * 16 + l16) * 1024 + kt0 + kt * 32 + quad * 8);
        int kn = (kt0 + 64) & 1023;   // wrap on last tile (harmless dummy prefetch)
        for (int nt = 0; nt < 4; ++nt)
            for (int kt = 0; kt < 2; ++kt)
                nxt[nt][kt] = *(const short8*)(kbase + (size_t)(kn + nt * 16 + l16) * 64 + kt * 32 + quad * 8);
        // S = Q K^T (waits only on cur-K, issued one iteration ago)
        f32x4 sacc[2][4];
        for (int mt = 0; mt < 2; ++mt)
            for (int nt = 0; nt < 4; ++nt) {
                f32x4 z = (f32x4)0.f;
                z = MFMA16(qf[mt][0], cur[nt][0], z);
                z = MFMA16(qf[mt][1], cur[nt][1], z);
                sacc[mt][nt] = z;
            }
        // P = exp2(scale*S + mask'); exact (scores bounded, fp32-safe)
        for (int mt = 0; mt < 2; ++mt)
            for (int nt = 0; nt < 4; ++nt)
                for (int r = 0; r < 4; ++r) {
                    float p = EXP2F(sacc[mt][nt][r] * KSCALE + mv[nt]);
                    Ps[wave][mt * 16 + quad * 4 + r][nt * 16 + l16] = f2bf(p);
                }
        // per-wave LDS: in-wave ordering + lgkmcnt suffice (no barrier)
        short8 pf[2][2];
        for (int mt = 0; mt < 2; ++mt)
            for (int kt = 0; kt < 2; ++kt)
                pf[mt][kt] = *(const short8*)&Ps[wave][mt * 16 + l16][kt * 32 + quad * 8];
        for (int mt = 0; mt < 2; ++mt) {
            for (int nt = 0; nt < 4; ++nt) {
                oacc[mt][nt] = MFMA16(pf[mt][0], vf[nt][0], oacc[mt][nt]);
                oacc[mt][nt] = MFMA16(pf[mt][1], vf[nt][1], oacc[mt][nt]);
            }
            sum_acc[mt] = MFMA16(pf[mt][0], ones, sum_acc[mt]);   // row sums of P
            sum_acc[mt] = MFMA16(pf[mt][1], ones, sum_acc[mt]);
        }
    };

    for (int it = 0; it < 16; it += 2) {
        body(it,     kfA, kfB);
        body(it + 1, kfB, kfA);
    }

    for (int mt = 0; mt < 2; ++mt) {
        for (int r = 0; r < 4; ++r) {
            float inv = 1.f / sum_acc[mt][r];
            int s = q0 + mt * 16 + quad * 4 + r;
            size_t ob = ((size_t)b * 1024 + s) * 1024 + h * 64;
            for (int nt = 0; nt < 4; ++nt)
                out[ob + nt * 16 + l16] = oacc[mt][nt][r] * inv;
        }
    }
}

extern "C" void kernel_launch(void* const* d_in, const int* in_sizes, int n_in,
                              void* d_out, int out_size, void* d_ws, size_t ws_size,
                              hipStream_t stream)
{
    const float* hidden = (const float*)d_in[0];
    const float* mask   = (const float*)d_in[1];
    const float* cosp   = (const float*)d_in[2];
    const float* sinp   = (const float*)d_in[3];
    const int* adapter_mask = (const int*)d_in[4];
    const float* W      = (const float*)d_in[5];
    const float* bias   = (const float*)d_in[6];
    const float* loraA  = (const float*)d_in[7];
    const float* loraB  = (const float*)d_in[8];
    float* out = (float*)d_out;

    char* ws = (char*)d_ws;
    float4* lo = (float4*)ws;                                  // 128 KB
    ushort_t* qw = (ushort_t*)(ws + (1 << 20));                // 16 MB each
    ushort_t* kw = qw + (size_t)8 * 16 * 1024 * 64;
    ushort_t* vt = kw + (size_t)8 * 16 * 1024 * 64;            // total 49 MB (proven fits)

    // bf16 copies of H and W live in d_out (32 MB); attn fully overwrites d_out afterwards
    ushort_t* Hb = (ushort_t*)d_out;                           // 16 MB
    ushort_t* Wb = Hb + (size_t)8192 * 1024;                   // 6 MB

    conv_bf16_kernel<<<11264, 256, 0, stream>>>((const float4*)hidden, (const float4*)W,
                                                (uint2*)Hb, (uint2*)Wb);
    lora_lo_kernel<<<8192, 64, 0, stream>>>(hidden, loraA, adapter_mask, lo);
    qkv_gemm_kernel<<<dim3(24, 64), 256, 0, stream>>>(Hb, Wb, bias, lo, loraB, adapter_mask,
                                                      cosp, sinp, qw, kw, vt);
    attn_kernel<<<1024, 256, 0, stream>>>(qw, kw, vt, mask, out);
}

// Round 8
// 322.384 us; speedup vs baseline: 1.1364x; 1.0851x over previous
//
#include <hip/hip_runtime.h>
#include <hip/hip_bf16.h>
#include <stdint.h>

typedef __attribute__((ext_vector_type(8))) short short8;
typedef __attribute__((ext_vector_type(4))) float f32x4;
typedef unsigned short ushort_t;

#define MFMA16(a, b, c) __builtin_amdgcn_mfma_f32_16x16x32_bf16((a), (b), (c), 0, 0, 0)
#define EXP2F(x) __builtin_amdgcn_exp2f(x)

// B=8 S=1024 D=1024 H=16 hd=64; M = B*S = 8192; N = 3*D = 3072; K = 1024

__device__ __forceinline__ float bf2f(unsigned short u) {
    union { unsigned int i; float f; } x; x.i = ((unsigned int)u) << 16; return x.f;
}
__device__ __forceinline__ unsigned short f2bf(float f) {
    union { float f; unsigned int i; } x; x.f = f;
    unsigned int i = x.i;
    i = i + 0x7FFFu + ((i >> 16) & 1u);   // RNE
    return (unsigned short)(i >> 16);
}
__device__ __forceinline__ unsigned int pack2(float a, float b) {
    return (unsigned int)f2bf(a) | ((unsigned int)f2bf(b) << 16);
}
__device__ __forceinline__ void glds16(const void* gsrc, void* ldst) {
    __builtin_amdgcn_global_load_lds(
        (const __attribute__((address_space(1))) unsigned int*)gsrc,
        (__attribute__((address_space(3))) unsigned int*)ldst, 16, 0, 0);
}

// ---------------- kernel 0: fp32 -> bf16 pre-pass for H and W ----------------
__global__ __launch_bounds__(256) void conv_bf16_kernel(
    const float4* __restrict__ H,   // 8192*1024 floats = 2097152 float4
    const float4* __restrict__ W,   // 3072*1024 floats =  786432 float4
    uint2* __restrict__ Hb,
    uint2* __restrict__ Wb)
{
    const size_t HN4 = 2097152;
    size_t i = (size_t)blockIdx.x * 256 + threadIdx.x;   // 0 .. 2883583
    const float4* src; uint2* dst; size_t j;
    if (i < HN4) { src = H; dst = Hb; j = i; }
    else         { src = W; dst = Wb; j = i - HN4; }
    float4 v = src[j];
    uint2 o; o.x = pack2(v.x, v.y); o.y = pack2(v.z, v.w);
    dst[j] = o;
}

// ---------------- kernel 1: lo(b,s,r) = sum_d hidden[b,s,d] * loraA[a_b][r][d] ----------------
__global__ __launch_bounds__(64) void lora_lo_kernel(
    const float* __restrict__ hidden,
    const float* __restrict__ loraA,
    const int* __restrict__ adapter_mask,
    float4* __restrict__ lo)
{
    int bs = blockIdx.x;          // 0..8191
    int lane = threadIdx.x;       // 0..63
    int b = bs >> 10;
    int a = adapter_mask[b];
    const float* hp = hidden + (size_t)bs * 1024 + lane * 16;
    const float* Ap = loraA + (size_t)a * 4096 + lane * 16;
    float hv[16];
    for (int j = 0; j < 16; ++j) hv[j] = hp[j];
    float acc[4];
    for (int r = 0; r < 4; ++r) {
        const float* ap = Ap + r * 1024;
        float s = 0.f;
        for (int j = 0; j < 16; ++j) s += hv[j] * ap[j];
        acc[r] = s;
    }
    for (int off = 32; off > 0; off >>= 1)
        for (int r = 0; r < 4; ++r) acc[r] += __shfl_xor(acc[r], off);
    if (lane == 0) lo[bs] = make_float4(acc[0], acc[1], acc[2], acc[3]);
}

// ---------------- kernel 2: qkv = Hb @ Wb^T + bias + 0.25 * lo @ B_t^T, fused RoPE ----------------
// q,k -> (B,H,S,hd) bf16 with RoPE applied; v -> transposed (B,H,hd,S) bf16
__global__ __launch_bounds__(256) void qkv_gemm_kernel(
    const ushort_t* __restrict__ Hb,   // (8192,1024) bf16
    const ushort_t* __restrict__ Wb,   // (3072,1024) bf16
    const float* __restrict__ bias,    // (3072)
    const float4* __restrict__ lo,     // (8192)
    const float* __restrict__ loraB,   // (5,3072,4)
    const int* __restrict__ adapter_mask, // (8)
    const float* __restrict__ cosp,    // (8,1024,64)
    const float* __restrict__ sinp,
    ushort_t* __restrict__ qw,
    ushort_t* __restrict__ kw,
    ushort_t* __restrict__ vt)
{
    __shared__ __align__(16) ushort_t As[128 * 32];   // no pad: global_load_lds layout
    __shared__ __align__(16) ushort_t Bs[128 * 32];
    int tid = threadIdx.x;
    int wave = tid >> 6, lane = tid & 63, quad = lane >> 4, l16 = lane & 15;
    int n0 = blockIdx.x * 128;
    int m0 = blockIdx.y * 128;
    int mq = (wave >> 1) * 64, nq = (wave & 1) * 64;

    f32x4 acc[4][4];
    for (int i = 0; i < 4; ++i) for (int j = 0; j < 4; ++j) acc[i][j] = (f32x4)0.f;

    const ushort_t* gA0 = Hb + (size_t)(m0 + (tid >> 2)) * 1024 + (tid & 3) * 8;
    const ushort_t* gA1 = gA0 + (size_t)64 * 1024;
    const ushort_t* gB0 = Wb + (size_t)(n0 + (tid >> 2)) * 1024 + (tid & 3) * 8;
    const ushort_t* gB1 = gB0 + (size_t)64 * 1024;
    char* ldsA0 = (char*)As + wave * 1024;            // + lane*16 implicit
    char* ldsA1 = ldsA0 + 4096;
    char* ldsB0 = (char*)Bs + wave * 1024;
    char* ldsB1 = ldsB0 + 4096;

    for (int kk = 0; kk < 1024; kk += 32) {
        glds16(gA0 + kk, ldsA0);
        glds16(gA1 + kk, ldsA1);
        glds16(gB0 + kk, ldsB0);
        glds16(gB1 + kk, ldsB1);
        __syncthreads();
        short8 af[4], bf[4];
        for (int mi = 0; mi < 4; ++mi)
            af[mi] = *(const short8*)&As[(mq + mi * 16 + l16) * 32 + quad * 8];
        for (int ni = 0; ni < 4; ++ni)
            bf[ni] = *(const short8*)&Bs[(nq + ni * 16 + l16) * 32 + quad * 8];
        for (int mi = 0; mi < 4; ++mi)
            for (int ni = 0; ni < 4; ++ni)
                acc[mi][ni] = MFMA16(af[mi], bf[ni], acc[mi][ni]);
        __syncthreads();
    }

    // epilogue: bias + lora + rope + scatter
    int t = n0 >> 10;            // 0=q 1=k 2=v, block-uniform (128 | 1024)
    int b = m0 >> 10;            // block-uniform
    int a = adapter_mask[b];
    float bi[4], bb[4][4];
    int cpos[4], chh[4];
    for (int ni = 0; ni < 4; ++ni) {
        int c = n0 + nq + ni * 16 + l16;
        bi[ni] = bias[c];
        const float* Bp = loraB + ((size_t)a * 3072 + c) * 4;
        bb[ni][0] = Bp[0]; bb[ni][1] = Bp[1]; bb[ni][2] = Bp[2]; bb[ni][3] = Bp[3];
        cpos[ni] = c & 63; chh[ni] = (c >> 6) & 15;
    }
    for (int mi = 0; mi < 4; ++mi) {
        float vals[4][4];   // [r][ni]
        for (int r = 0; r < 4; ++r) {
            int m = m0 + mq + mi * 16 + quad * 4 + r;
            float4 lov = lo[m];
            for (int ni = 0; ni < 4; ++ni)
                vals[r][ni] = acc[mi][ni][r] + bi[ni]
                      + 0.25f * (lov.x * bb[ni][0] + lov.y * bb[ni][1]
                               + lov.z * bb[ni][2] + lov.w * bb[ni][3]);
        }
        int s0 = (m0 + mq + mi * 16 + quad * 4) & 1023;
        if (t < 2) {
            for (int r = 0; r < 4; ++r) {
                int s = s0 + r;
                // rope: pos = ni*16+l16 for ni<2, partner at ni+2 (pos+32); cos[pos+32]==cos[pos]
                size_t cb = ((size_t)b * 1024 + s) * 64;
                float cA = cosp[cb + l16],      sA = sinp[cb + l16];
                float cB = cosp[cb + 16 + l16], sB = sinp[cb + 16 + l16];
                float w0 = vals[r][0] * cA - vals[r][2] * sA;
                float w2 = vals[r][2] * cA + vals[r][0] * sA;
                float w1 = vals[r][1] * cB - vals[r][3] * sB;
                float w3 = vals[r][3] * cB + vals[r][1] * sB;
                float v[4] = {w0, w1, w2, w3};
                for (int ni = 0; ni < 4; ++ni) {
                    size_t bh = (size_t)b * 16 + chh[ni];
                    ushort_t ob = f2bf(v[ni]);
                    if (t == 0) qw[(bh * 1024 + s) * 64 + cpos[ni]] = ob;
                    else        kw[(bh * 1024 + s) * 64 + cpos[ni]] = ob;
                }
            }
        } else {
            // v: pack 4 consecutive s (r=0..3) into one 8B store
            for (int ni = 0; ni < 4; ++ni) {
                uint2 pk;
                pk.x = pack2(vals[0][ni], vals[1][ni]);
                pk.y = pack2(vals[2][ni], vals[3][ni]);
                size_t bh = (size_t)b * 16 + chh[ni];
                *(uint2*)&vt[(bh * 64 + cpos[ni]) * 1024 + s0] = pk;
            }
        }
    }
}

// ---------------- kernel 3: attention, two independent 64-key tile chains per iteration ----------------
// grid 1024 = 8 q-tiles(128 rows) x 128 bh; id%8 == bh%8 -> XCD-local K/V (L2-resident 4MB/XCD).
// Tiles A (kt0) and B (kt0+64) have independent K->QK->exp->Ps->PV chains; compiler interleaves
// them so one chain's LDS-roundtrip/exp stalls are filled by the other's work (in-wave ILP).
__global__ __launch_bounds__(256) void attn_kernel(
    const ushort_t* __restrict__ qw,   // (B,H,S,hd) bf16 (rope applied)
    const ushort_t* __restrict__ kw,   // (B,H,S,hd) bf16 (rope applied)
    const ushort_t* __restrict__ vt,   // (B,H,hd,S) bf16
    const float* __restrict__ mask,    // (B,1,1,S) f32
    float* __restrict__ out)           // (B,S,H*hd) f32
{
    __shared__ __align__(16) ushort_t Ps[4][2][32][72];   // per-wave, per-tile(A/B)
    __shared__ float mlds[1024];
    const float KSCALE = 0.125f * 1.44269504f;
    const float MSCALE = 1.44269504f;
    int tid = threadIdx.x;
    int wave = tid >> 6, lane = tid & 63, quad = lane >> 4, l16 = lane & 15;
    int id = blockIdx.x;
    int qt = id >> 7;             // 0..7
    int bh = id & 127;            // 0..127
    int b = bh >> 4, h = bh & 15;
    size_t base = (size_t)bh * 1024 * 64;
    int q0 = qt * 128 + wave * 32;

    // stage mask row (pre-scaled) into LDS once
    for (int i = tid; i < 1024; i += 256) mlds[i] = mask[b * 1024 + i] * MSCALE;
    __syncthreads();

    short8 ones;
    for (int j = 0; j < 8; ++j) ones[j] = (short)0x3F80;   // bf16 1.0

    const ushort_t* kbase = kw + base;
    const ushort_t* vbase = vt + base;

    short8 qf[2][2];
    for (int mt = 0; mt < 2; ++mt)
        for (int kt = 0; kt < 2; ++kt)
            qf[mt][kt] = *(const short8*)(qw + base + (size_t)(q0 + mt * 16 + l16) * 64 + kt * 32 + quad * 8);

    f32x4 oacc[2][4], sum_acc[2];
    for (int mt = 0; mt < 2; ++mt) {
        sum_acc[mt] = (f32x4)0.f;
        for (int nt = 0; nt < 4; ++nt) oacc[mt][nt] = (f32x4)0.f;
    }

    for (int it = 0; it < 8; ++it) {
        int ka = it * 128;        // tile A
        int kb = ka + 64;         // tile B
        // ---- issue all global loads first: K_A, K_B, V_A, V_B ----
        short8 kfA[4][2], kfB[4][2];
        for (int nt = 0; nt < 4; ++nt)
            for (int kt = 0; kt < 2; ++kt) {
                kfA[nt][kt] = *(const short8*)(kbase + (size_t)(ka + nt * 16 + l16) * 64 + kt * 32 + quad * 8);
                kfB[nt][kt] = *(const short8*)(kbase + (size_t)(kb + nt * 16 + l16) * 64 + kt * 32 + quad * 8);
            }
        short8 vfA[4][2], vfB[4][2];
        for (int nt = 0; nt < 4; ++nt)
            for (int kt = 0; kt < 2; ++kt) {
                vfA[nt][kt] = *(const short8*)(vbase + (size_t)(nt * 16 + l16) * 1024 + ka + kt * 32 + quad * 8);
                vfB[nt][kt] = *(const short8*)(vbase + (size_t)(nt * 16 + l16) * 1024 + kb + kt * 32 + quad * 8);
            }
        float mvA[4], mvB[4];
        for (int nt = 0; nt < 4; ++nt) {
            mvA[nt] = mlds[ka + nt * 16 + l16];
            mvB[nt] = mlds[kb + nt * 16 + l16];
        }
        // ---- chain A and chain B, independent until accumulation ----
        f32x4 saccA[2][4], saccB[2][4];
        for (int mt = 0; mt < 2; ++mt)
            for (int nt = 0; nt < 4; ++nt) {
                f32x4 za = (f32x4)0.f;
                za = MFMA16(qf[mt][0], kfA[nt][0], za);
                za = MFMA16(qf[mt][1], kfA[nt][1], za);
                saccA[mt][nt] = za;
                f32x4 zb = (f32x4)0.f;
                zb = MFMA16(qf[mt][0], kfB[nt][0], zb);
                zb = MFMA16(qf[mt][1], kfB[nt][1], zb);
                saccB[mt][nt] = zb;
            }
        for (int mt = 0; mt < 2; ++mt)
            for (int nt = 0; nt < 4; ++nt)
                for (int r = 0; r < 4; ++r) {
                    float pa = EXP2F(saccA[mt][nt][r] * KSCALE + mvA[nt]);
                    Ps[wave][0][mt * 16 + quad * 4 + r][nt * 16 + l16] = f2bf(pa);
                    float pb = EXP2F(saccB[mt][nt][r] * KSCALE + mvB[nt]);
                    Ps[wave][1][mt * 16 + quad * 4 + r][nt * 16 + l16] = f2bf(pb);
                }
        // per-wave LDS: in-wave ordering + lgkmcnt suffice (no barrier)
        short8 pfA[2][2], pfB[2][2];
        for (int mt = 0; mt < 2; ++mt)
            for (int kt = 0; kt < 2; ++kt) {
                pfA[mt][kt] = *(const short8*)&Ps[wave][0][mt * 16 + l16][kt * 32 + quad * 8];
                pfB[mt][kt] = *(const short8*)&Ps[wave][1][mt * 16 + l16][kt * 32 + quad * 8];
            }
        for (int mt = 0; mt < 2; ++mt) {
            for (int nt = 0; nt < 4; ++nt) {
                oacc[mt][nt] = MFMA16(pfA[mt][0], vfA[nt][0], oacc[mt][nt]);
                oacc[mt][nt] = MFMA16(pfA[mt][1], vfA[nt][1], oacc[mt][nt]);
                oacc[mt][nt] = MFMA16(pfB[mt][0], vfB[nt][0], oacc[mt][nt]);
                oacc[mt][nt] = MFMA16(pfB[mt][1], vfB[nt][1], oacc[mt][nt]);
            }
            sum_acc[mt] = MFMA16(pfA[mt][0], ones, sum_acc[mt]);
            sum_acc[mt] = MFMA16(pfA[mt][1], ones, sum_acc[mt]);
            sum_acc[mt] = MFMA16(pfB[mt][0], ones, sum_acc[mt]);
            sum_acc[mt] = MFMA16(pfB[mt][1], ones, sum_acc[mt]);
        }
    }

    for (int mt = 0; mt < 2; ++mt) {
        for (int r = 0; r < 4; ++r) {
            float inv = 1.f / sum_acc[mt][r];
            int s = q0 + mt * 16 + quad * 4 + r;
            size_t ob = ((size_t)b * 1024 + s) * 1024 + h * 64;
            for (int nt = 0; nt < 4; ++nt)
                out[ob + nt * 16 + l16] = oacc[mt][nt][r] * inv;
        }
    }
}

extern "C" void kernel_launch(void* const* d_in, const int* in_sizes, int n_in,
                              void* d_out, int out_size, void* d_ws, size_t ws_size,
                              hipStream_t stream)
{
    const float* hidden = (const float*)d_in[0];
    const float* mask   = (const float*)d_in[1];
    const float* cosp   = (const float*)d_in[2];
    const float* sinp   = (const float*)d_in[3];
    const int* adapter_mask = (const int*)d_in[4];
    const float* W      = (const float*)d_in[5];
    const float* bias   = (const float*)d_in[6];
    const float* loraA  = (const float*)d_in[7];
    const float* loraB  = (const float*)d_in[8];
    float* out = (float*)d_out;

    char* ws = (char*)d_ws;
    float4* lo = (float4*)ws;                                  // 128 KB
    ushort_t* qw = (ushort_t*)(ws + (1 << 20));                // 16 MB each
    ushort_t* kw = qw + (size_t)8 * 16 * 1024 * 64;
    ushort_t* vt = kw + (size_t)8 * 16 * 1024 * 64;            // total 49 MB (proven fits)

    // bf16 copies of H and W live in d_out (32 MB); attn fully overwrites d_out afterwards
    ushort_t* Hb = (ushort_t*)d_out;                           // 16 MB
    ushort_t* Wb = Hb + (size_t)8192 * 1024;                   // 6 MB

    conv_bf16_kernel<<<11264, 256, 0, stream>>>((const float4*)hidden, (const float4*)W,
                                                (uint2*)Hb, (uint2*)Wb);
    lora_lo_kernel<<<8192, 64, 0, stream>>>(hidden, loraA, adapter_mask, lo);
    qkv_gemm_kernel<<<dim3(24, 64), 256, 0, stream>>>(Hb, Wb, bias, lo, loraB, adapter_mask,
                                                      cosp, sinp, qw, kw, vt);
    attn_kernel<<<1024, 256, 0, stream>>>(qw, kw, vt, mask, out);
}

// Round 9
// 260.331 us; speedup vs baseline: 1.4073x; 1.2384x over previous
//
#include <hip/hip_runtime.h>
#include <hip/hip_bf16.h>
#include <stdint.h>

typedef __attribute__((ext_vector_type(8))) short short8;
typedef __attribute__((ext_vector_type(4))) float f32x4;
typedef unsigned short ushort_t;

#define MFMA16(a, b, c) __builtin_amdgcn_mfma_f32_16x16x32_bf16((a), (b), (c), 0, 0, 0)
#define EXP2F(x) __builtin_amdgcn_exp2f(x)

// B=8 S=1024 D=1024 H=16 hd=64; M = B*S = 8192; N = 3*D = 3072; K = 1024

__device__ __forceinline__ float bf2f(unsigned short u) {
    union { unsigned int i; float f; } x; x.i = ((unsigned int)u) << 16; return x.f;
}
__device__ __forceinline__ unsigned short f2bf(float f) {
    union { float f; unsigned int i; } x; x.f = f;
    unsigned int i = x.i;
    i = i + 0x7FFFu + ((i >> 16) & 1u);   // RNE
    return (unsigned short)(i >> 16);
}
__device__ __forceinline__ unsigned int pack2(float a, float b) {
    return (unsigned int)f2bf(a) | ((unsigned int)f2bf(b) << 16);
}
__device__ __forceinline__ void glds16(const void* gsrc, void* ldst) {
    __builtin_amdgcn_global_load_lds(
        (const __attribute__((address_space(1))) unsigned int*)gsrc,
        (__attribute__((address_space(3))) unsigned int*)ldst, 16, 0, 0);
}

// ---------------- kernel 1: fused prep — bf16 convert of H,W + lora lo ----------------
__global__ __launch_bounds__(64) void prep_kernel(
    const float* __restrict__ hidden,   // (8192,1024)
    const float* __restrict__ W,        // (3072,1024)
    const float* __restrict__ loraA,    // (5,4,1024)
    const int* __restrict__ adapter_mask,
    ushort_t* __restrict__ Hb,
    ushort_t* __restrict__ Wb,
    float4* __restrict__ lo)
{
    int blk = blockIdx.x;         // 0..11263
    int lane = threadIdx.x;       // 0..63
    if (blk < 8192) {
        int b = blk >> 10;
        int a = adapter_mask[b];
        const float* hp = hidden + (size_t)blk * 1024 + lane * 16;
        float hv[16];
        for (int j = 0; j < 16; ++j) hv[j] = hp[j];
        uint4 p0, p1;
        p0.x = pack2(hv[0], hv[1]);  p0.y = pack2(hv[2], hv[3]);
        p0.z = pack2(hv[4], hv[5]);  p0.w = pack2(hv[6], hv[7]);
        p1.x = pack2(hv[8], hv[9]);  p1.y = pack2(hv[10], hv[11]);
        p1.z = pack2(hv[12], hv[13]); p1.w = pack2(hv[14], hv[15]);
        uint4* hd = (uint4*)(Hb + (size_t)blk * 1024 + lane * 16);
        hd[0] = p0; hd[1] = p1;
        const float* Ap = loraA + (size_t)a * 4096 + lane * 16;
        float acc[4];
        for (int r = 0; r < 4; ++r) {
            const float* ap = Ap + r * 1024;
            float s = 0.f;
            for (int j = 0; j < 16; ++j) s += hv[j] * ap[j];
            acc[r] = s;
        }
        for (int off = 32; off > 0; off >>= 1)
            for (int r = 0; r < 4; ++r) acc[r] += __shfl_xor(acc[r], off);
        if (lane == 0) lo[blk] = make_float4(acc[0], acc[1], acc[2], acc[3]);
    } else {
        int row = blk - 8192;     // 0..3071
        const float* wp = W + (size_t)row * 1024 + lane * 16;
        float wv[16];
        for (int j = 0; j < 16; ++j) wv[j] = wp[j];
        uint4 p0, p1;
        p0.x = pack2(wv[0], wv[1]);  p0.y = pack2(wv[2], wv[3]);
        p0.z = pack2(wv[4], wv[5]);  p0.w = pack2(wv[6], wv[7]);
        p1.x = pack2(wv[8], wv[9]);  p1.y = pack2(wv[10], wv[11]);
        p1.z = pack2(wv[12], wv[13]); p1.w = pack2(wv[14], wv[15]);
        uint4* wd = (uint4*)(Wb + (size_t)row * 1024 + lane * 16);
        wd[0] = p0; wd[1] = p1;
    }
}

// ---------------- kernel 2: qkv = Hb @ Wb^T + bias + 0.25 * lo @ B_t^T, fused RoPE ----------------
__global__ __launch_bounds__(256) void qkv_gemm_kernel(
    const ushort_t* __restrict__ Hb,   // (8192,1024) bf16
    const ushort_t* __restrict__ Wb,   // (3072,1024) bf16
    const float* __restrict__ bias,    // (3072)
    const float4* __restrict__ lo,     // (8192)
    const float* __restrict__ loraB,   // (5,3072,4)
    const int* __restrict__ adapter_mask, // (8)
    const float* __restrict__ cosp,    // (8,1024,64)
    const float* __restrict__ sinp,
    ushort_t* __restrict__ qw,
    ushort_t* __restrict__ kw,
    ushort_t* __restrict__ vt)
{
    __shared__ __align__(16) ushort_t As[128 * 32];   // no pad: global_load_lds layout
    __shared__ __align__(16) ushort_t Bs[128 * 32];
    int tid = threadIdx.x;
    int wave = tid >> 6, lane = tid & 63, quad = lane >> 4, l16 = lane & 15;
    int n0 = blockIdx.x * 128;
    int m0 = blockIdx.y * 128;
    int mq = (wave >> 1) * 64, nq = (wave & 1) * 64;

    f32x4 acc[4][4];
    for (int i = 0; i < 4; ++i) for (int j = 0; j < 4; ++j) acc[i][j] = (f32x4)0.f;

    const ushort_t* gA0 = Hb + (size_t)(m0 + (tid >> 2)) * 1024 + (tid & 3) * 8;
    const ushort_t* gA1 = gA0 + (size_t)64 * 1024;
    const ushort_t* gB0 = Wb + (size_t)(n0 + (tid >> 2)) * 1024 + (tid & 3) * 8;
    const ushort_t* gB1 = gB0 + (size_t)64 * 1024;
    char* ldsA0 = (char*)As + wave * 1024;            // + lane*16 implicit
    char* ldsA1 = ldsA0 + 4096;
    char* ldsB0 = (char*)Bs + wave * 1024;
    char* ldsB1 = ldsB0 + 4096;

    for (int kk = 0; kk < 1024; kk += 32) {
        glds16(gA0 + kk, ldsA0);
        glds16(gA1 + kk, ldsA1);
        glds16(gB0 + kk, ldsB0);
        glds16(gB1 + kk, ldsB1);
        __syncthreads();
        short8 af[4], bf[4];
        for (int mi = 0; mi < 4; ++mi)
            af[mi] = *(const short8*)&As[(mq + mi * 16 + l16) * 32 + quad * 8];
        for (int ni = 0; ni < 4; ++ni)
            bf[ni] = *(const short8*)&Bs[(nq + ni * 16 + l16) * 32 + quad * 8];
        for (int mi = 0; mi < 4; ++mi)
            for (int ni = 0; ni < 4; ++ni)
                acc[mi][ni] = MFMA16(af[mi], bf[ni], acc[mi][ni]);
        __syncthreads();
    }

    // epilogue: bias + lora + rope + scatter
    int t = n0 >> 10;            // 0=q 1=k 2=v, block-uniform (128 | 1024)
    int b = m0 >> 10;            // block-uniform
    int a = adapter_mask[b];
    float bi[4], bb[4][4];
    int cpos[4], chh[4];
    for (int ni = 0; ni < 4; ++ni) {
        int c = n0 + nq + ni * 16 + l16;
        bi[ni] = bias[c];
        const float* Bp = loraB + ((size_t)a * 3072 + c) * 4;
        bb[ni][0] = Bp[0]; bb[ni][1] = Bp[1]; bb[ni][2] = Bp[2]; bb[ni][3] = Bp[3];
        cpos[ni] = c & 63; chh[ni] = (c >> 6) & 15;
    }
    for (int mi = 0; mi < 4; ++mi) {
        float vals[4][4];   // [r][ni]
        for (int r = 0; r < 4; ++r) {
            int m = m0 + mq + mi * 16 + quad * 4 + r;
            float4 lov = lo[m];
            for (int ni = 0; ni < 4; ++ni)
                vals[r][ni] = acc[mi][ni][r] + bi[ni]
                      + 0.25f * (lov.x * bb[ni][0] + lov.y * bb[ni][1]
                               + lov.z * bb[ni][2] + lov.w * bb[ni][3]);
        }
        int s0 = (m0 + mq + mi * 16 + quad * 4) & 1023;
        if (t < 2) {
            for (int r = 0; r < 4; ++r) {
                int s = s0 + r;
                size_t cb = ((size_t)b * 1024 + s) * 64;
                float cA = cosp[cb + l16],      sA = sinp[cb + l16];
                float cB = cosp[cb + 16 + l16], sB = sinp[cb + 16 + l16];
                float w0 = vals[r][0] * cA - vals[r][2] * sA;
                float w2 = vals[r][2] * cA + vals[r][0] * sA;
                float w1 = vals[r][1] * cB - vals[r][3] * sB;
                float w3 = vals[r][3] * cB + vals[r][1] * sB;
                float v[4] = {w0, w1, w2, w3};
                for (int ni = 0; ni < 4; ++ni) {
                    size_t bh = (size_t)b * 16 + chh[ni];
                    ushort_t ob = f2bf(v[ni]);
                    if (t == 0) qw[(bh * 1024 + s) * 64 + cpos[ni]] = ob;
                    else        kw[(bh * 1024 + s) * 64 + cpos[ni]] = ob;
                }
            }
        } else {
            for (int ni = 0; ni < 4; ++ni) {
                uint2 pk;
                pk.x = pack2(vals[0][ni], vals[1][ni]);
                pk.y = pack2(vals[2][ni], vals[3][ni]);
                size_t bh = (size_t)b * 16 + chh[ni];
                *(uint2*)&vt[(bh * 64 + cpos[ni]) * 1024 + s0] = pk;
            }
        }
    }
}

// ---------------- kernel 3: attention, K+V staged in LDS via glds16 (XOR-swizzled), dbuf ----------------
// grid 1024 = 8 q-tiles(128 rows) x 128 bh; id%8 == bh%8 -> XCD-local K/V.
// Tile = 64 keys. K tile 8KB, V tile 8KB, stored as 512 16B-chunks with chunk swizzle
// c_phys = c_log ^ (row&7) -> ds_read_b128 row-walks are bank-conflict-free.
// No per-lane VGPR load destinations: staging is pure DMA, fragments come from LDS.
__global__ __launch_bounds__(256) void attn_kernel(
    const ushort_t* __restrict__ qw,   // (B,H,S,hd) bf16 (rope applied)
    const ushort_t* __restrict__ kw,   // (B,H,S,hd) bf16 (rope applied)
    const ushort_t* __restrict__ vt,   // (B,H,hd,S) bf16
    const float* __restrict__ mask,    // (B,1,1,S) f32
    float* __restrict__ out)           // (B,S,H*hd) f32
{
    __shared__ __align__(16) ushort_t Kt[2][4096];    // 8KB per buf
    __shared__ __align__(16) ushort_t Vt[2][4096];
    __shared__ __align__(16) ushort_t Ps[4][32][72];  // per-wave
    __shared__ float mlds[1024];
    const float KSCALE = 0.125f * 1.44269504f;
    int tid = threadIdx.x;
    int wave = tid >> 6, lane = tid & 63, quad = lane >> 4, l16 = lane & 15;
    int id = blockIdx.x;
    int qt = id >> 7;             // 0..7
    int bh = id & 127;            // 0..127
    int b = bh >> 4, h = bh & 15;
    size_t base = (size_t)bh * 65536;
    int q0 = qt * 128 + wave * 32;

    for (int i = tid; i < 1024; i += 256) mlds[i] = mask[b * 1024 + i] * 1.44269504f;

    const ushort_t* kbase = kw + base;
    const ushort_t* vbase = vt + base;

    // staging geometry: thread handles chunks n0 = tid, n1 = tid + 256 of each 512-chunk tile
    int n0 = tid, n1 = tid + 256;
    int r0 = n0 >> 3, c0 = (n0 & 7) ^ (r0 & 7);   // logical row, swizzled source chunk
    int r1 = n1 >> 3, c1 = (n1 & 7) ^ (r1 & 7);
    // LDS dests (wave-uniform base + lane*16)
    char* kd0[2] = { (char*)&Kt[0][0] + wave * 1024, (char*)&Kt[1][0] + wave * 1024 };
    char* vd0[2] = { (char*)&Vt[0][0] + wave * 1024, (char*)&Vt[1][0] + wave * 1024 };

    short8 qf[2][2];
    for (int mt = 0; mt < 2; ++mt)
        for (int kt = 0; kt < 2; ++kt)
            qf[mt][kt] = *(const short8*)(qw + base + (size_t)(q0 + mt * 16 + l16) * 64 + kt * 32 + quad * 8);

    f32x4 oacc[2][4], sum_acc[2];
    for (int mt = 0; mt < 2; ++mt) {
        sum_acc[mt] = (f32x4)0.f;
        for (int nt = 0; nt < 4; ++nt) oacc[mt][nt] = (f32x4)0.f;
    }

    short8 ones;
    for (int j = 0; j < 8; ++j) ones[j] = (short)0x3F80;   // bf16 1.0

    // prefetch tile 0 into buf 0
    glds16(kbase + (size_t)r0 * 64 + c0 * 8, kd0[0]);
    glds16(kbase + (size_t)r1 * 64 + c1 * 8, kd0[0] + 4096);
    glds16(vbase + (size_t)r0 * 1024 + c0 * 8, vd0[0]);
    glds16(vbase + (size_t)r1 * 1024 + c1 * 8, vd0[0] + 4096);

    // precompute fragment LDS offsets (ushort index)
    int koff[4][2], voff[4][2];
    for (int nt = 0; nt < 4; ++nt)
        for (int kt = 0; kt < 2; ++kt) {
            int rr = nt * 16 + l16;
            int cc = (kt * 4 + quad) ^ (rr & 7);
            koff[nt][kt] = (rr * 8 + cc) * 8;
            voff[nt][kt] = (rr * 8 + cc) * 8;   // same geometry (V rows are d)
        }

    for (int it = 0; it < 16; ++it) {
        int cur = it & 1;
        int kt0 = it * 64;
        __syncthreads();          // vmcnt(0) drain: buf[cur] staged
        if (it < 15) {
            int kn = kt0 + 64;
            int nxt = cur ^ 1;
            glds16(kbase + (size_t)(kn + r0) * 64 + c0 * 8, kd0[nxt]);
            glds16(kbase + (size_t)(kn + r1) * 64 + c1 * 8, kd0[nxt] + 4096);
            glds16(vbase + (size_t)r0 * 1024 + kn + c0 * 8, vd0[nxt]);
            glds16(vbase + (size_t)r1 * 1024 + kn + c1 * 8, vd0[nxt] + 4096);
        }
        // S = Q K^T
        short8 kf[4][2];
        for (int nt = 0; nt < 4; ++nt)
            for (int kt = 0; kt < 2; ++kt)
                kf[nt][kt] = *(const short8*)&Kt[cur][koff[nt][kt]];
        f32x4 sacc[2][4];
        for (int mt = 0; mt < 2; ++mt)
            for (int nt = 0; nt < 4; ++nt) {
                f32x4 z = (f32x4)0.f;
                z = MFMA16(qf[mt][0], kf[nt][0], z);
                z = MFMA16(qf[mt][1], kf[nt][1], z);
                sacc[mt][nt] = z;
            }
        float mv[4];
        for (int nt = 0; nt < 4; ++nt) mv[nt] = mlds[kt0 + nt * 16 + l16];
        // P = exp2(scale*S + mask'); exact (scores bounded, fp32-safe)
        for (int mt = 0; mt < 2; ++mt)
            for (int nt = 0; nt < 4; ++nt)
                for (int r = 0; r < 4; ++r) {
                    float p = EXP2F(sacc[mt][nt][r] * KSCALE + mv[nt]);
                    Ps[wave][mt * 16 + quad * 4 + r][nt * 16 + l16] = f2bf(p);
                }
        short8 pf[2][2];
        for (int mt = 0; mt < 2; ++mt)
            for (int kt = 0; kt < 2; ++kt)
                pf[mt][kt] = *(const short8*)&Ps[wave][mt * 16 + l16][kt * 32 + quad * 8];
        short8 vf[4][2];
        for (int nt = 0; nt < 4; ++nt)
            for (int kt = 0; kt < 2; ++kt)
                vf[nt][kt] = *(const short8*)&Vt[cur][voff[nt][kt]];
        for (int mt = 0; mt < 2; ++mt) {
            for (int nt = 0; nt < 4; ++nt) {
                oacc[mt][nt] = MFMA16(pf[mt][0], vf[nt][0], oacc[mt][nt]);
                oacc[mt][nt] = MFMA16(pf[mt][1], vf[nt][1], oacc[mt][nt]);
            }
            sum_acc[mt] = MFMA16(pf[mt][0], ones, sum_acc[mt]);
            sum_acc[mt] = MFMA16(pf[mt][1], ones, sum_acc[mt]);
        }
    }

    for (int mt = 0; mt < 2; ++mt) {
        for (int r = 0; r < 4; ++r) {
            float inv = 1.f / sum_acc[mt][r];
            int s = q0 + mt * 16 + quad * 4 + r;
            size_t ob = ((size_t)b * 1024 + s) * 1024 + h * 64;
            for (int nt = 0; nt < 4; ++nt)
                out[ob + nt * 16 + l16] = oacc[mt][nt][r] * inv;
        }
    }
}

extern "C" void kernel_launch(void* const* d_in, const int* in_sizes, int n_in,
                              void* d_out, int out_size, void* d_ws, size_t ws_size,
                              hipStream_t stream)
{
    const float* hidden = (const float*)d_in[0];
    const float* mask   = (const float*)d_in[1];
    const float* cosp   = (const float*)d_in[2];
    const float* sinp   = (const float*)d_in[3];
    const int* adapter_mask = (const int*)d_in[4];
    const float* W      = (const float*)d_in[5];
    const float* bias   = (const float*)d_in[6];
    const float* loraA  = (const float*)d_in[7];
    const float* loraB  = (const float*)d_in[8];
    float* out = (float*)d_out;

    char* ws = (char*)d_ws;
    float4* lo = (float4*)ws;                                  // 128 KB
    ushort_t* qw = (ushort_t*)(ws + (1 << 20));                // 16 MB each
    ushort_t* kw = qw + (size_t)8 * 16 * 1024 * 64;
    ushort_t* vt = kw + (size_t)8 * 16 * 1024 * 64;            // total 49 MB (proven fits)

    // bf16 copies of H and W live in d_out (32 MB); attn fully overwrites d_out afterwards
    ushort_t* Hb = (ushort_t*)d_out;                           // 16 MB
    ushort_t* Wb = Hb + (size_t)8192 * 1024;                   // 6 MB

    prep_kernel<<<11264, 64, 0, stream>>>(hidden, W, loraA, adapter_mask, Hb, Wb, lo);
    qkv_gemm_kernel<<<dim3(24, 64), 256, 0, stream>>>(Hb, Wb, bias, lo, loraB, adapter_mask,
                                                      cosp, sinp, qw, kw, vt);
    attn_kernel<<<1024, 256, 0, stream>>>(qw, kw, vt, mask, out);
}